// Round 2
// baseline (205.625 us; speedup 1.0000x reference)
//
#include <hip/hip_runtime.h>

#define NUM_NODES 100000
#define INPUT_DIM 256
#define NUM_BAGS  2048
#define BAG_SIZE  64
#define N_EDGES   3200000
#define NXCD      8

// HW_REG_XCC_ID = 20 (gfx940+); simm16 = id | (offset<<6) | ((size-1)<<11)
// Measured on MI355X (learn_hip m09): returns 0..7.
__device__ __forceinline__ unsigned xcd_id() {
    return __builtin_amdgcn_s_getreg(20 | (3 << 11)) & (NXCD - 1);
}

// Pass 1: per-source neighbor weight sums + degree flag.
// PRIVATE_L2 path: atomics go to this XCD's private replica with
// workgroup-scope (no sc1) -> executed in the local L2, not memory-side.
// All writers of replica r live on XCD r, so the weaker scope is sufficient;
// end-of-kernel release writes the dirty L2 lines back.
template <bool PRIVATE_L2>
__global__ void __launch_bounds__(256)
edge_accum(const int* __restrict__ edge_src,
           const int* __restrict__ edge_nbr,
           const float* __restrict__ node_weights,
           float* __restrict__ rep,          // [NXCD][NUM_NODES] or [1][NUM_NODES]
           unsigned int* __restrict__ deg) {
    float* __restrict__ my =
        PRIVATE_L2 ? rep + (size_t)xcd_id() * NUM_NODES : rep;

    const int t = blockIdx.x * blockDim.x + threadIdx.x;  // one quad of edges
    const int4 s4 = ((const int4*)edge_src)[t];
    const int4 n4 = ((const int4*)edge_nbr)[t];
    const float w0 = node_weights[n4.x];
    const float w1 = node_weights[n4.y];
    const float w2 = node_weights[n4.z];
    const float w3 = node_weights[n4.w];

    if (PRIVATE_L2) {
        __hip_atomic_fetch_add(&my[s4.x], w0, __ATOMIC_RELAXED, __HIP_MEMORY_SCOPE_WORKGROUP);
        __hip_atomic_fetch_add(&my[s4.y], w1, __ATOMIC_RELAXED, __HIP_MEMORY_SCOPE_WORKGROUP);
        __hip_atomic_fetch_add(&my[s4.z], w2, __ATOMIC_RELAXED, __HIP_MEMORY_SCOPE_WORKGROUP);
        __hip_atomic_fetch_add(&my[s4.w], w3, __ATOMIC_RELAXED, __HIP_MEMORY_SCOPE_WORKGROUP);
    } else {
        atomicAdd(&my[s4.x], w0);
        atomicAdd(&my[s4.y], w1);
        atomicAdd(&my[s4.z], w2);
        atomicAdd(&my[s4.w], w3);
    }
    deg[s4.x] = 1u;  // benign race: all writers store 1
    deg[s4.y] = 1u;
    deg[s4.z] = 1u;
    deg[s4.w] = 1u;
}

// Pass 2: one block (4 waves) per bag. Per item, 64 lanes hold float4 of the
// 256-dim row (coalesced 1KB), butterfly-reduce the dot, scale by
// (sum over replicas of nbr_sum) * alpha.
template <int NREP>
__global__ void __launch_bounds__(256)
bag_kernel(const float* __restrict__ x,
           const int* __restrict__ bags,
           const float* __restrict__ alpha,
           const float* __restrict__ rep,    // [NREP][NUM_NODES]
           const unsigned int* __restrict__ deg,
           const float* __restrict__ theta,
           float* __restrict__ out) {
    const int bag  = blockIdx.x;
    const int lane = threadIdx.x & 63;
    const int wave = threadIdx.x >> 6;

    const float4 tw = *reinterpret_cast<const float4*>(&theta[lane * 4]);

    float acc = 0.f;
    for (int item = wave; item < BAG_SIZE; item += 4) {
        const int idx = bags[bag * BAG_SIZE + item];
        const float4 xv =
            *reinterpret_cast<const float4*>(&x[(long)idx * INPUT_DIM + lane * 4]);
        float d = xv.x * tw.x + xv.y * tw.y + xv.z * tw.z + xv.w * tw.w;
        #pragma unroll
        for (int off = 32; off >= 1; off >>= 1)
            d += __shfl_xor(d, off);

        float ns;
        if (deg[idx]) {
            ns = 0.f;
            #pragma unroll
            for (int r = 0; r < NREP; ++r)
                ns += rep[(size_t)r * NUM_NODES + idx];   // uniform-addr, L2-hit
        } else {
            ns = 1.0f;
        }
        const float a = alpha[bag * BAG_SIZE + item];
        acc += ns * a * d;
    }

    __shared__ float wred[4];
    if (lane == 0) wred[wave] = acc;
    __syncthreads();
    if (threadIdx.x == 0)
        out[bag] = wred[0] + wred[1] + wred[2] + wred[3];
}

extern "C" void kernel_launch(void* const* d_in, const int* in_sizes, int n_in,
                              void* d_out, int out_size, void* d_ws, size_t ws_size,
                              hipStream_t stream) {
    const float* x            = (const float*)d_in[0];
    const int*   bags         = (const int*)d_in[1];
    const float* alpha        = (const float*)d_in[2];
    const int*   edge_src     = (const int*)d_in[3];
    const int*   edge_nbr     = (const int*)d_in[4];
    const float* node_weights = (const float*)d_in[5];
    const float* theta        = (const float*)d_in[6];
    float*       out          = (float*)d_out;

    const size_t need = ((size_t)NXCD * NUM_NODES + NUM_NODES) * 4;
    const int nquadblk = (N_EDGES / 4) / 256;   // 3125 exact

    if (ws_size >= need) {
        float*        rep = (float*)d_ws;                       // [8][NUM_NODES]
        unsigned int* deg = (unsigned int*)d_ws + (size_t)NXCD * NUM_NODES;
        hipMemsetAsync(d_ws, 0, need, stream);
        edge_accum<true><<<nquadblk, 256, 0, stream>>>(edge_src, edge_nbr,
                                                       node_weights, rep, deg);
        bag_kernel<NXCD><<<NUM_BAGS, 256, 0, stream>>>(x, bags, alpha, rep, deg,
                                                       theta, out);
    } else {
        float*        rep = (float*)d_ws;                       // [1][NUM_NODES]
        unsigned int* deg = (unsigned int*)d_ws + NUM_NODES;
        hipMemsetAsync(d_ws, 0, (size_t)NUM_NODES * 2 * 4, stream);
        edge_accum<false><<<nquadblk, 256, 0, stream>>>(edge_src, edge_nbr,
                                                        node_weights, rep, deg);
        bag_kernel<1><<<NUM_BAGS, 256, 0, stream>>>(x, bags, alpha, rep, deg,
                                                    theta, out);
    }
}

// Round 3
// 88.146 us; speedup vs baseline: 2.3328x; 2.3328x over previous
//
#include <hip/hip_runtime.h>

#define NUM_NODES 100000
#define INPUT_DIM 256
#define NUM_BAGS  2048
#define BAG_SIZE  64
#define N_EDGES   3200000
#define P_PART    8
#define NPP       12500   // nodes per partition: 8 * 12500 = 100000; 50 KB LDS

// Pass 1: LDS-privatized histogram. Grid = P_PART * B blocks.
// Block (p, b): histogram of node range [p*NPP, (p+1)*NPP) over edge slice b.
// Each edge is accumulated by exactly one block (the one whose partition
// contains its src) via LDS fp atomics; flush is non-atomic to rep[b][*].
// The 8 blocks sharing slice b are consecutive blockIds -> concurrent ->
// the 8x edge re-read stays L3-resident (25.6 MB << 256 MB).
template <int B>
__global__ void __launch_bounds__(1024)
edge_hist(const int* __restrict__ edge_src, const int* __restrict__ edge_nbr,
          const float* __restrict__ nw,
          float* __restrict__ rep,            // [B][NUM_NODES], fully overwritten
          unsigned int* __restrict__ deg) {   // pre-zeroed
    __shared__ float hist[NPP];
    const int p    = blockIdx.x & (P_PART - 1);
    const int b    = blockIdx.x >> 3;
    const int base = p * NPP;

    for (int j = threadIdx.x; j < NPP; j += 1024) hist[j] = 0.f;
    __syncthreads();

    const int nq  = N_EDGES / 4;     // 800000 int4 quads
    const int per = nq / B;          // exact for B in {8,16,32}
    const int lo  = b * per;
    const int hi  = lo + per;
    for (int i = lo + (int)threadIdx.x; i < hi; i += 1024) {
        const int4 s4 = ((const int4*)edge_src)[i];
        const int4 n4 = ((const int4*)edge_nbr)[i];
#define EDGE(S, N)                                                   \
        {                                                            \
            const unsigned rel = (unsigned)((S) - base);             \
            if (rel < (unsigned)NPP) {                               \
                atomicAdd(&hist[rel], nw[(N)]);  /* ds_add_f32 */    \
                deg[(S)] = 1u;  /* benign race, L2-absorbed */       \
            }                                                        \
        }
        EDGE(s4.x, n4.x)
        EDGE(s4.y, n4.y)
        EDGE(s4.z, n4.z)
        EDGE(s4.w, n4.w)
#undef EDGE
    }
    __syncthreads();

    float* dst = rep + (size_t)b * NUM_NODES + base;
    for (int j = threadIdx.x; j < NPP; j += 1024) dst[j] = hist[j];
}

// Pass 1b: nbr_sum[n] = deg[n] ? sum_b rep[b][n] : 1.0
template <int B>
__global__ void __launch_bounds__(256)
reduce_rep(const float* __restrict__ rep, const unsigned int* __restrict__ deg,
           float* __restrict__ nbr_sum) {
    const int i = blockIdx.x * 256 + threadIdx.x;   // float4 index
    if (i >= NUM_NODES / 4) return;
    float4 a = make_float4(0.f, 0.f, 0.f, 0.f);
    for (int r = 0; r < B; ++r) {
        const float4 v = ((const float4*)(rep + (size_t)r * NUM_NODES))[i];
        a.x += v.x; a.y += v.y; a.z += v.z; a.w += v.w;
    }
    const uint4 d = ((const uint4*)deg)[i];
    float4 o;
    o.x = d.x ? a.x : 1.0f;
    o.y = d.y ? a.y : 1.0f;
    o.z = d.z ? a.z : 1.0f;
    o.w = d.w ? a.w : 1.0f;
    ((float4*)nbr_sum)[i] = o;
}

// Fallback pass 1 (tiny ws): plain device atomics (round-1 behavior).
__global__ void __launch_bounds__(256)
edge_atomic(const int* __restrict__ edge_src, const int* __restrict__ edge_nbr,
            const float* __restrict__ nw,
            float* __restrict__ nbr_sum, unsigned int* __restrict__ deg) {
    const int t = blockIdx.x * blockDim.x + threadIdx.x;
    const int4 s4 = ((const int4*)edge_src)[t];
    const int4 n4 = ((const int4*)edge_nbr)[t];
    atomicAdd(&nbr_sum[s4.x], nw[n4.x]);
    atomicAdd(&nbr_sum[s4.y], nw[n4.y]);
    atomicAdd(&nbr_sum[s4.z], nw[n4.z]);
    atomicAdd(&nbr_sum[s4.w], nw[n4.w]);
    deg[s4.x] = 1u; deg[s4.y] = 1u; deg[s4.z] = 1u; deg[s4.w] = 1u;
}

__global__ void __launch_bounds__(256)
fixup_nosum(float* __restrict__ nbr_sum, const unsigned int* __restrict__ deg) {
    const int i = blockIdx.x * 256 + threadIdx.x;
    if (i < NUM_NODES && deg[i] == 0u) nbr_sum[i] = 1.0f;
}

// Pass 2: one block (4 waves) per bag; 64 lanes hold float4 of the 256-dim
// row (coalesced 1KB), butterfly-reduce the dot, scale by nbr_sum * alpha.
__global__ void __launch_bounds__(256)
bag_kernel(const float* __restrict__ x,
           const int* __restrict__ bags,
           const float* __restrict__ alpha,
           const float* __restrict__ nbr_sum,   // finished (deg folded in)
           const float* __restrict__ theta,
           float* __restrict__ out) {
    const int bag  = blockIdx.x;
    const int lane = threadIdx.x & 63;
    const int wave = threadIdx.x >> 6;

    const float4 tw = *reinterpret_cast<const float4*>(&theta[lane * 4]);

    float acc = 0.f;
    for (int item = wave; item < BAG_SIZE; item += 4) {
        const int idx = bags[bag * BAG_SIZE + item];
        const float4 xv =
            *reinterpret_cast<const float4*>(&x[(long)idx * INPUT_DIM + lane * 4]);
        float d = xv.x * tw.x + xv.y * tw.y + xv.z * tw.z + xv.w * tw.w;
        #pragma unroll
        for (int off = 32; off >= 1; off >>= 1)
            d += __shfl_xor(d, off);
        acc += nbr_sum[idx] * alpha[bag * BAG_SIZE + item] * d;
    }

    __shared__ float wred[4];
    if (lane == 0) wred[wave] = acc;
    __syncthreads();
    if (threadIdx.x == 0)
        out[bag] = wred[0] + wred[1] + wred[2] + wred[3];
}

template <int B>
static void run_hist_path(const int* edge_src, const int* edge_nbr,
                          const float* nw, const float* x, const int* bags,
                          const float* alpha, const float* theta, float* out,
                          void* d_ws, hipStream_t stream) {
    float*        rep     = (float*)d_ws;                              // [B][NUM_NODES]
    unsigned int* deg     = (unsigned int*)d_ws + (size_t)B * NUM_NODES;
    float*        nbr_sum = (float*)deg + NUM_NODES;

    hipMemsetAsync(deg, 0, (size_t)NUM_NODES * sizeof(unsigned int), stream);
    edge_hist<B><<<P_PART * B, 1024, 0, stream>>>(edge_src, edge_nbr, nw, rep, deg);
    reduce_rep<B><<<(NUM_NODES / 4 + 255) / 256, 256, 0, stream>>>(rep, deg, nbr_sum);
    bag_kernel<<<NUM_BAGS, 256, 0, stream>>>(x, bags, alpha, nbr_sum, theta, out);
}

extern "C" void kernel_launch(void* const* d_in, const int* in_sizes, int n_in,
                              void* d_out, int out_size, void* d_ws, size_t ws_size,
                              hipStream_t stream) {
    const float* x            = (const float*)d_in[0];
    const int*   bags         = (const int*)d_in[1];
    const float* alpha        = (const float*)d_in[2];
    const int*   edge_src     = (const int*)d_in[3];
    const int*   edge_nbr     = (const int*)d_in[4];
    const float* node_weights = (const float*)d_in[5];
    const float* theta        = (const float*)d_in[6];
    float*       out          = (float*)d_out;

    auto need = [](int B) {
        return ((size_t)B * NUM_NODES + 2 * NUM_NODES) * sizeof(float);
    };

    if (ws_size >= need(32)) {
        run_hist_path<32>(edge_src, edge_nbr, node_weights, x, bags, alpha,
                          theta, out, d_ws, stream);
    } else if (ws_size >= need(16)) {
        run_hist_path<16>(edge_src, edge_nbr, node_weights, x, bags, alpha,
                          theta, out, d_ws, stream);
    } else if (ws_size >= need(8)) {
        run_hist_path<8>(edge_src, edge_nbr, node_weights, x, bags, alpha,
                         theta, out, d_ws, stream);
    } else {
        // Tiny-ws fallback: device atomics.
        float*        nbr_sum = (float*)d_ws;
        unsigned int* deg     = (unsigned int*)d_ws + NUM_NODES;
        hipMemsetAsync(d_ws, 0, (size_t)NUM_NODES * 2 * sizeof(float), stream);
        edge_atomic<<<(N_EDGES / 4) / 256, 256, 0, stream>>>(
            edge_src, edge_nbr, node_weights, nbr_sum, deg);
        fixup_nosum<<<(NUM_NODES + 255) / 256, 256, 0, stream>>>(nbr_sum, deg);
        bag_kernel<<<NUM_BAGS, 256, 0, stream>>>(x, bags, alpha, nbr_sum, theta, out);
    }
}

// Round 4
// 76.353 us; speedup vs baseline: 2.6931x; 1.1545x over previous
//
#include <hip/hip_runtime.h>

#define NUM_NODES 100000
#define INPUT_DIM 256
#define NUM_BAGS  2048
#define BAG_SIZE  64
#define N_EDGES   3200000
#define P_PART    8
#define NPP       12500   // 8 * 12500 = 100000; 50 KB static LDS
#define NSLICE    32      // edge slices; grid = 8 * 32 = 256 blocks

// Pass 1: LDS-privatized histogram, XCD-swizzled.
// blockIdx bits: [2:0]=r (XCD via round-robin dispatch), [5:3]=p (partition),
// [7:6]=b_hi. Slice b = r | (b_hi<<3)  ->  all 8 partition-blocks of a slice
// share XCD r, so the slice's 800 KB of edge data is read from HBM once and
// re-read 8x from that XCD's private L2 (3.2 MB edges + 0.4 MB nw < 4 MB L2).
__global__ void __launch_bounds__(1024)
edge_hist(const int* __restrict__ edge_src, const int* __restrict__ edge_nbr,
          const float* __restrict__ nw,
          float* __restrict__ rep,            // [NSLICE][NUM_NODES], overwritten
          unsigned int* __restrict__ deg) {   // pre-zeroed
    __shared__ float hist[NPP];
    const int i    = blockIdx.x;
    const int r    = i & 7;
    const int p    = (i >> 3) & 7;
    const int b    = r | ((i >> 6) << 3);
    const int base = p * NPP;

    for (int j = threadIdx.x; j < NPP; j += 1024) hist[j] = 0.f;
    __syncthreads();

    const int per = (N_EDGES / 4) / NSLICE;   // 25000 quads / slice
    const int lo  = b * per;
    const int hi  = lo + per;
    for (int q = lo + (int)threadIdx.x; q < hi; q += 1024) {
        const int4 s4 = ((const int4*)edge_src)[q];
        const int4 n4 = ((const int4*)edge_nbr)[q];
#define EDGE(S, N)                                                   \
        {                                                            \
            const unsigned rel = (unsigned)((S) - base);             \
            if (rel < (unsigned)NPP) {                               \
                atomicAdd(&hist[rel], nw[(N)]);  /* ds_add_f32 */    \
                deg[(S)] = 1u;  /* benign race */                    \
            }                                                        \
        }
        EDGE(s4.x, n4.x)
        EDGE(s4.y, n4.y)
        EDGE(s4.z, n4.z)
        EDGE(s4.w, n4.w)
#undef EDGE
    }
    __syncthreads();

    float* dst = rep + (size_t)b * NUM_NODES + base;
    for (int j = threadIdx.x; j < NPP; j += 1024) dst[j] = hist[j];
}

// Pass 1b: nbr_sum[n] = deg[n] ? sum_b rep[b][n] : 1.0
__global__ void __launch_bounds__(256)
reduce_rep(const float* __restrict__ rep, const unsigned int* __restrict__ deg,
           float* __restrict__ nbr_sum) {
    const int i = blockIdx.x * 256 + threadIdx.x;   // float4 index
    if (i >= NUM_NODES / 4) return;
    float4 a = make_float4(0.f, 0.f, 0.f, 0.f);
    for (int r = 0; r < NSLICE; ++r) {
        const float4 v = ((const float4*)(rep + (size_t)r * NUM_NODES))[i];
        a.x += v.x; a.y += v.y; a.z += v.z; a.w += v.w;
    }
    const uint4 d = ((const uint4*)deg)[i];
    float4 o;
    o.x = d.x ? a.x : 1.0f;
    o.y = d.y ? a.y : 1.0f;
    o.z = d.z ? a.z : 1.0f;
    o.w = d.w ? a.w : 1.0f;
    ((float4*)nbr_sum)[i] = o;
}

// Pass 2a: h[n] = theta . x[n]  — dense coalesced GEMV over ALL nodes
// (102 MB streamed once beats gathering 134 MB of duplicate rows).
__global__ void __launch_bounds__(256)
gemv_h(const float* __restrict__ x, const float* __restrict__ theta,
       float* __restrict__ h) {
    const int lane = threadIdx.x & 63;
    const int wave = threadIdx.x >> 6;
    const float4 tw = *reinterpret_cast<const float4*>(&theta[lane * 4]);
    const int stride = gridDim.x * 4;
    for (int row = blockIdx.x * 4 + wave; row < NUM_NODES; row += stride) {
        const float4 xv =
            *reinterpret_cast<const float4*>(&x[(size_t)row * INPUT_DIM + lane * 4]);
        float d = xv.x * tw.x + xv.y * tw.y + xv.z * tw.z + xv.w * tw.w;
        #pragma unroll
        for (int off = 32; off >= 1; off >>= 1)
            d += __shfl_xor(d, off);
        if (lane == 0) h[row] = d;
    }
}

// Pass 2b: out[bag] = sum_item h[idx] * nbr_sum[idx] * alpha — one wave/bag,
// lane = item; h and nbr_sum are 400 KB tables (L2/L3-resident).
__global__ void __launch_bounds__(256)
bag_final(const int* __restrict__ bags, const float* __restrict__ alpha,
          const float* __restrict__ h, const float* __restrict__ ns,
          float* __restrict__ out) {
    const int bag  = blockIdx.x * 4 + (threadIdx.x >> 6);
    const int lane = threadIdx.x & 63;
    const int idx  = bags[bag * BAG_SIZE + lane];
    float v = h[idx] * ns[idx] * alpha[bag * BAG_SIZE + lane];
    #pragma unroll
    for (int off = 32; off >= 1; off >>= 1)
        v += __shfl_xor(v, off);
    if (lane == 0) out[bag] = v;
}

// Fallback pass 1 (small ws): plain device atomics.
__global__ void __launch_bounds__(256)
edge_atomic(const int* __restrict__ edge_src, const int* __restrict__ edge_nbr,
            const float* __restrict__ nw,
            float* __restrict__ nbr_sum, unsigned int* __restrict__ deg) {
    const int t = blockIdx.x * blockDim.x + threadIdx.x;
    const int4 s4 = ((const int4*)edge_src)[t];
    const int4 n4 = ((const int4*)edge_nbr)[t];
    atomicAdd(&nbr_sum[s4.x], nw[n4.x]);
    atomicAdd(&nbr_sum[s4.y], nw[n4.y]);
    atomicAdd(&nbr_sum[s4.z], nw[n4.z]);
    atomicAdd(&nbr_sum[s4.w], nw[n4.w]);
    deg[s4.x] = 1u; deg[s4.y] = 1u; deg[s4.z] = 1u; deg[s4.w] = 1u;
}

__global__ void __launch_bounds__(256)
fixup_nosum(float* __restrict__ nbr_sum, const unsigned int* __restrict__ deg) {
    const int i = blockIdx.x * 256 + threadIdx.x;
    if (i < NUM_NODES && deg[i] == 0u) nbr_sum[i] = 1.0f;
}

extern "C" void kernel_launch(void* const* d_in, const int* in_sizes, int n_in,
                              void* d_out, int out_size, void* d_ws, size_t ws_size,
                              hipStream_t stream) {
    const float* x            = (const float*)d_in[0];
    const int*   bags         = (const int*)d_in[1];
    const float* alpha        = (const float*)d_in[2];
    const int*   edge_src     = (const int*)d_in[3];
    const int*   edge_nbr     = (const int*)d_in[4];
    const float* node_weights = (const float*)d_in[5];
    const float* theta        = (const float*)d_in[6];
    float*       out          = (float*)d_out;

    // ws layout (full path): rep[32][100000] f32 | deg[100000] u32 |
    //                        nbr_sum[100000] f32 | h[100000] f32
    const size_t need_full =
        ((size_t)NSLICE * NUM_NODES + 3 * (size_t)NUM_NODES) * 4;

    if (ws_size >= need_full) {
        float*        rep     = (float*)d_ws;
        unsigned int* deg     = (unsigned int*)d_ws + (size_t)NSLICE * NUM_NODES;
        float*        nbr_sum = (float*)deg + NUM_NODES;
        float*        h       = nbr_sum + NUM_NODES;

        hipMemsetAsync(deg, 0, (size_t)NUM_NODES * 4, stream);
        edge_hist<<<P_PART * NSLICE, 1024, 0, stream>>>(edge_src, edge_nbr,
                                                        node_weights, rep, deg);
        gemv_h<<<2048, 256, 0, stream>>>(x, theta, h);
        reduce_rep<<<(NUM_NODES / 4 + 255) / 256, 256, 0, stream>>>(rep, deg,
                                                                    nbr_sum);
        bag_final<<<NUM_BAGS / 4, 256, 0, stream>>>(bags, alpha, h, nbr_sum, out);
    } else {
        // Fallback: device atomics + same GEMV/bag structure (needs 1.2 MB).
        float*        nbr_sum = (float*)d_ws;
        unsigned int* deg     = (unsigned int*)d_ws + NUM_NODES;
        float*        h       = (float*)deg + NUM_NODES;
        hipMemsetAsync(d_ws, 0, (size_t)NUM_NODES * 2 * 4, stream);
        edge_atomic<<<(N_EDGES / 4) / 256, 256, 0, stream>>>(
            edge_src, edge_nbr, node_weights, nbr_sum, deg);
        fixup_nosum<<<(NUM_NODES + 255) / 256, 256, 0, stream>>>(nbr_sum, deg);
        gemv_h<<<2048, 256, 0, stream>>>(x, theta, h);
        bag_final<<<NUM_BAGS / 4, 256, 0, stream>>>(bags, alpha, h, nbr_sum, out);
    }
}